// Round 1
// baseline (480.826 us; speedup 1.0000x reference)
//
#include <hip/hip_runtime.h>
#include <math.h>

#define B_  32
#define C_  256
#define T_  64      // 8*8 pooled tokens
#define HW_ 4096    // 64*64 plane

// ---------------- Kernel 1: 8x8 average pool of both inputs ----------------
// grid: B*C blocks, 256 threads. Each block pools one (b,c) plane of F_rgb and F_d.
__global__ __launch_bounds__(256) void k_pool(const float* __restrict__ Frgb,
                                              const float* __restrict__ Fd,
                                              float* __restrict__ R,
                                              float* __restrict__ D) {
    __shared__ float s[128];
    const int tid = threadIdx.x;
    const int plane = blockIdx.x;
    if (tid < 128) s[tid] = 0.f;
    __syncthreads();
    const float4* pr = (const float4*)Frgb + (size_t)plane * 1024;
    const float4* pd = (const float4*)Fd   + (size_t)plane * 1024;
    const int cellx = (tid & 15) >> 1;   // (tid%16)/2
    const int hbit  = tid >> 7;          // tid/128
    #pragma unroll
    for (int k = 0; k < 4; ++k) {
        const int cell = (2*k + hbit) * 8 + cellx;
        float4 a = pr[k*256 + tid];
        atomicAdd(&s[cell], a.x + a.y + a.z + a.w);
        float4 b = pd[k*256 + tid];
        atomicAdd(&s[64 + cell], b.x + b.y + b.z + b.w);
    }
    __syncthreads();
    if (tid < 64)        R[(size_t)plane*64 + tid]        = s[tid]      * (1.f/64.f);
    else if (tid < 128)  D[(size_t)plane*64 + (tid - 64)] = s[tid]      * (1.f/64.f);
}

// ---------------- Kernel 2a: Q/K/V = W @ X + bias ----------------
// grid: (4 t-tiles, 32 batches, 3 {Q,K,V}), 256 threads.
// thread tid owns output channel o = tid; accumulates a 16-wide t-tile.
// W chunk staged transposed in LDS -> conflict-free b32 reads (lane-consecutive o).
// X rows are wave-uniform -> scalar loads.
__global__ __launch_bounds__(256) void k_qkv(const float* __restrict__ R, const float* __restrict__ D,
                                             const float* __restrict__ Wq, const float* __restrict__ bq,
                                             const float* __restrict__ Wk, const float* __restrict__ bk,
                                             const float* __restrict__ Wv, const float* __restrict__ bv,
                                             float* __restrict__ Q, float* __restrict__ K,
                                             float* __restrict__ V) {
    __shared__ float Ws[32 * 256];   // [c_local][o] transposed chunk, 32 KB
    const int tid = threadIdx.x;
    const int tbase = blockIdx.x * 16;
    const int b = blockIdx.y;
    const int z = blockIdx.z;
    const float* W    = (z == 0) ? Wq : (z == 1) ? Wk : Wv;
    const float* bias = (z == 0) ? bq : (z == 1) ? bk : bv;
    const float* X    = (z == 0) ? R  : D;
    float* Out        = (z == 0) ? Q  : (z == 1) ? K  : V;

    const int o = tid;
    float acc[16];
    const float bz = bias[o];
    #pragma unroll
    for (int t = 0; t < 16; ++t) acc[t] = bz;

    const float* Xb = X + (size_t)b * C_ * T_;
    for (int cb = 0; cb < 256; cb += 32) {
        __syncthreads();
        // stage W[0:256][cb:cb+32] transposed: each thread copies its own row chunk
        #pragma unroll
        for (int k = 0; k < 8; ++k) {
            float4 w4 = *(const float4*)(W + (size_t)o * 256 + cb + k*4);
            Ws[(k*4 + 0)*256 + o] = w4.x;
            Ws[(k*4 + 1)*256 + o] = w4.y;
            Ws[(k*4 + 2)*256 + o] = w4.z;
            Ws[(k*4 + 3)*256 + o] = w4.w;
        }
        __syncthreads();
        for (int cl = 0; cl < 32; ++cl) {
            const float w = Ws[cl*256 + o];
            const float* xrow = Xb + (size_t)(cb + cl) * T_ + tbase;  // wave-uniform
            #pragma unroll
            for (int t = 0; t < 16; ++t) acc[t] += w * xrow[t];
        }
    }
    float* orow = Out + ((size_t)b * C_ + o) * T_ + tbase;
    #pragma unroll
    for (int t = 0; t < 16; ++t) orow[t] = acc[t];
}

// ---------------- Kernel 2b: per-batch attention ----------------
// grid: 32 blocks (one per batch), 256 threads (4 waves).
// Phase A: A[t][s] = sum_c Q[c,t] K[c,s]; lane = s, wave owns a 16-row t-tile.
// Softmax over s entirely in registers (64-lane butterflies).
// Phase PV: Fatt[c][t] = sum_s V[c,s] A[t,s]; lane = t, wave owns 64 channels.
__global__ __launch_bounds__(256) void k_attn(const float* __restrict__ Q,
                                              const float* __restrict__ K,
                                              const float* __restrict__ V,
                                              float* __restrict__ Fatt) {
    __shared__ float Ks[128 * 64];   // half of K[b], 32 KB
    __shared__ float As[64 * 65];    // A transposed [s][t], pad 65 -> conflict-free
    const int tid  = threadIdx.x;
    const int lane = tid & 63;
    const int wv   = __builtin_amdgcn_readfirstlane(tid >> 6);
    const int b = blockIdx.x;

    float acc[16];
    #pragma unroll
    for (int t = 0; t < 16; ++t) acc[t] = 0.f;

    const float* Qb = Q + (size_t)b * C_ * T_;
    const float* Kb = K + (size_t)b * C_ * T_;
    for (int half = 0; half < 2; ++half) {
        __syncthreads();
        const float4* src = (const float4*)(Kb + half * 128 * 64);
        float4* dst = (float4*)Ks;
        #pragma unroll
        for (int k = 0; k < 8; ++k) dst[k*256 + tid] = src[k*256 + tid];
        __syncthreads();
        for (int cl = 0; cl < 128; ++cl) {
            const float kv = Ks[cl*64 + lane];
            const float* qrow = Qb + (size_t)(half*128 + cl) * T_ + wv*16;  // wave-uniform
            #pragma unroll
            for (int t = 0; t < 16; ++t) acc[t] += kv * qrow[t];
        }
    }

    // online-free softmax: rows are fully resident in the wave (lane = s)
    #pragma unroll
    for (int t = 0; t < 16; ++t) {
        float m = acc[t];
        #pragma unroll
        for (int off = 32; off; off >>= 1) m = fmaxf(m, __shfl_xor(m, off));
        const float e = __expf(acc[t] - m);
        float ssum = e;
        #pragma unroll
        for (int off = 32; off; off >>= 1) ssum += __shfl_xor(ssum, off);
        As[lane*65 + wv*16 + t] = e / ssum;
    }
    __syncthreads();

    // PV: preload this lane's A column (t = lane), dot with uniform V rows
    float av[64];
    #pragma unroll
    for (int s = 0; s < 64; ++s) av[s] = As[s*65 + lane];
    const float* Vb = V + (size_t)b * C_ * T_;
    float* Fb = Fatt + (size_t)b * C_ * T_;
    for (int cc = 0; cc < 64; ++cc) {
        const int c = wv*64 + cc;
        const float* vrow = Vb + (size_t)c * T_;   // wave-uniform
        float sum = 0.f;
        #pragma unroll
        for (int s = 0; s < 64; ++s) sum = fmaf(vrow[s], av[s], sum);
        Fb[(size_t)c * T_ + lane] = sum;
    }
}

// ---------------- Kernel 3: bilinear 8->64 upsample + blend ----------------
// grid: B*C blocks, 256 threads; half-pixel centers, edge clamp
// (matches jax.image.resize 'bilinear' upsampling / torch align_corners=False).
__global__ __launch_bounds__(256) void k_up(const float* __restrict__ Fatt,
                                            const float* __restrict__ Frgb,
                                            const float* __restrict__ alphap,
                                            float* __restrict__ Out) {
    __shared__ float Fs[64];
    const int tid = threadIdx.x;
    const int plane = blockIdx.x;
    if (tid < 64) Fs[tid] = Fatt[(size_t)plane*64 + tid];
    __syncthreads();
    const float alpha = alphap[0];
    const float beta = 1.f - alpha;
    const float4* rgb4 = (const float4*)Frgb + (size_t)plane * 1024;
    float4* out4 = (float4*)Out + (size_t)plane * 1024;
    #pragma unroll
    for (int k = 0; k < 4; ++k) {
        const int flat = k*1024 + tid*4;
        const int y  = flat >> 6;
        const int xb = flat & 63;
        const float sy = y * 0.125f - 0.4375f;
        const float fy = floorf(sy);
        const float wy = sy - fy;
        const int iy = (int)fy;
        const int y0 = iy < 0 ? 0 : iy;
        const int y1 = (iy + 1) > 7 ? 7 : (iy + 1);
        float4 rv = rgb4[k*256 + tid];
        float o[4];
        const float rs[4] = {rv.x, rv.y, rv.z, rv.w};
        #pragma unroll
        for (int j = 0; j < 4; ++j) {
            const int x = xb + j;
            const float sx = x * 0.125f - 0.4375f;
            const float fx = floorf(sx);
            const float wx = sx - fx;
            const int ix = (int)fx;
            const int x0 = ix < 0 ? 0 : ix;
            const int x1 = (ix + 1) > 7 ? 7 : (ix + 1);
            const float top = (1.f - wx) * Fs[y0*8 + x0] + wx * Fs[y0*8 + x1];
            const float bot = (1.f - wx) * Fs[y1*8 + x0] + wx * Fs[y1*8 + x1];
            const float v = (1.f - wy) * top + wy * bot;
            o[j] = alpha * v + beta * rs[j];
        }
        out4[k*256 + tid] = make_float4(o[0], o[1], o[2], o[3]);
    }
}

extern "C" void kernel_launch(void* const* d_in, const int* in_sizes, int n_in,
                              void* d_out, int out_size, void* d_ws, size_t ws_size,
                              hipStream_t stream) {
    const float* Frgb  = (const float*)d_in[0];
    const float* Fd    = (const float*)d_in[1];
    const float* Wq    = (const float*)d_in[2];
    const float* bq    = (const float*)d_in[3];
    const float* Wk    = (const float*)d_in[4];
    const float* bk    = (const float*)d_in[5];
    const float* Wv    = (const float*)d_in[6];
    const float* bv    = (const float*)d_in[7];
    const float* alpha = (const float*)d_in[8];

    float* ws = (float*)d_ws;
    const size_t PC = (size_t)B_ * C_ * T_;   // 524288 floats per pooled tensor
    float* R    = ws;
    float* D    = ws + PC;
    float* Q    = ws + 2*PC;
    float* K    = ws + 3*PC;
    float* V    = ws + 4*PC;
    float* Fatt = ws + 5*PC;
    float* Out  = (float*)d_out;

    k_pool<<<B_*C_, 256, 0, stream>>>(Frgb, Fd, R, D);
    k_qkv <<<dim3(4, 32, 3), 256, 0, stream>>>(R, D, Wq, bq, Wk, bk, Wv, bv, Q, K, V);
    k_attn<<<B_, 256, 0, stream>>>(Q, K, V, Fatt);
    k_up  <<<B_*C_, 256, 0, stream>>>(Fatt, Frgb, alpha, Out);
}

// Round 2
// 418.784 us; speedup vs baseline: 1.1481x; 1.1481x over previous
//
#include <hip/hip_runtime.h>
#include <math.h>

#define B_  32
#define C_  256
#define T_  64      // 8*8 pooled tokens
#define HW_ 4096    // 64*64 plane

// ---------------- Kernel 1: 8x8 average pool of both inputs ----------------
// grid: B*C blocks, 256 threads. Each block pools one (b,c) plane of F_rgb and F_d.
// No LDS atomics: register partials -> private LDS slots -> 128-thread gather.
__global__ __launch_bounds__(256) void k_pool(const float* __restrict__ Frgb,
                                              const float* __restrict__ Fd,
                                              float* __restrict__ R,
                                              float* __restrict__ D) {
    __shared__ float P[2][1024];   // [tensor][k*256+tid] per-thread partials, 8 KB
    const int tid = threadIdx.x;
    const int plane = blockIdx.x;
    const float4* pr = (const float4*)Frgb + (size_t)plane * 1024;
    const float4* pd = (const float4*)Fd   + (size_t)plane * 1024;
    #pragma unroll
    for (int k = 0; k < 4; ++k) {
        float4 a = pr[k*256 + tid];
        P[0][k*256 + tid] = a.x + a.y + a.z + a.w;
        float4 b = pd[k*256 + tid];
        P[1][k*256 + tid] = b.x + b.y + b.z + b.w;
    }
    __syncthreads();
    // cell (cy,cx): contributing partials at idx = (cy>>1)*256 + (cy&1)*128 + rg*16 + 2cx + e
    if (tid < 128) {
        const int tensor = tid >> 6;
        const int cell = tid & 63;
        const int cy = cell >> 3, cx = cell & 7;
        const int base = (cy >> 1)*256 + (cy & 1)*128 + 2*cx;
        float s = 0.f;
        #pragma unroll
        for (int rg = 0; rg < 8; ++rg)
            s += P[tensor][base + rg*16] + P[tensor][base + rg*16 + 1];
        float* dst = tensor ? D : R;
        dst[(size_t)plane*64 + cell] = s * (1.f/64.f);
    }
}

// ---------------- Kernel 2a: Q/K/V = W @ X + bias ----------------
// grid: (4 t-tiles, 32 batches, 3 {Q,K,V}), 256 threads.
// thread tid owns output channel o = tid; accumulates a 16-wide t-tile.
__global__ __launch_bounds__(256) void k_qkv(const float* __restrict__ R, const float* __restrict__ D,
                                             const float* __restrict__ Wq, const float* __restrict__ bq,
                                             const float* __restrict__ Wk, const float* __restrict__ bk,
                                             const float* __restrict__ Wv, const float* __restrict__ bv,
                                             float* __restrict__ Q, float* __restrict__ K,
                                             float* __restrict__ V) {
    __shared__ float Ws[32 * 256];   // [c_local][o] transposed chunk, 32 KB
    const int tid = threadIdx.x;
    const int tbase = blockIdx.x * 16;
    const int b = blockIdx.y;
    const int z = blockIdx.z;
    const float* W    = (z == 0) ? Wq : (z == 1) ? Wk : Wv;
    const float* bias = (z == 0) ? bq : (z == 1) ? bk : bv;
    const float* X    = (z == 0) ? R  : D;
    float* Out        = (z == 0) ? Q  : (z == 1) ? K  : V;

    const int o = tid;
    float acc[16];
    const float bz = bias[o];
    #pragma unroll
    for (int t = 0; t < 16; ++t) acc[t] = bz;

    const float* Xb = X + (size_t)b * C_ * T_;
    for (int cb = 0; cb < 256; cb += 32) {
        __syncthreads();
        #pragma unroll
        for (int k = 0; k < 8; ++k) {
            float4 w4 = *(const float4*)(W + (size_t)o * 256 + cb + k*4);
            Ws[(k*4 + 0)*256 + o] = w4.x;
            Ws[(k*4 + 1)*256 + o] = w4.y;
            Ws[(k*4 + 2)*256 + o] = w4.z;
            Ws[(k*4 + 3)*256 + o] = w4.w;
        }
        __syncthreads();
        for (int cl = 0; cl < 32; ++cl) {
            const float w = Ws[cl*256 + o];
            const float* xrow = Xb + (size_t)(cb + cl) * T_ + tbase;  // wave-uniform
            #pragma unroll
            for (int t = 0; t < 16; ++t) acc[t] += w * xrow[t];
        }
    }
    float* orow = Out + ((size_t)b * C_ + o) * T_ + tbase;
    #pragma unroll
    for (int t = 0; t < 16; ++t) orow[t] = acc[t];
}

// ---------------- Kernel 2b: per-batch A = softmax(Q^T K), stored transposed ----------------
// grid: 32 blocks (one per batch), 256 threads (4 waves).
// A[t][s] = sum_c Q[c,t] K[c,s]; lane = s, wave owns a 16-row t-tile.
// Softmax over s in registers (64-lane butterflies). Output AT[b][s][t].
__global__ __launch_bounds__(256) void k_attnA(const float* __restrict__ Q,
                                               const float* __restrict__ K,
                                               float* __restrict__ AT) {
    __shared__ float Ks[128 * 64];   // half of K[b], 32 KB
    __shared__ float As[64 * 65];    // A transposed [s][t], pad 65
    const int tid  = threadIdx.x;
    const int lane = tid & 63;
    const int wv   = __builtin_amdgcn_readfirstlane(tid >> 6);
    const int b = blockIdx.x;

    float acc[16];
    #pragma unroll
    for (int t = 0; t < 16; ++t) acc[t] = 0.f;

    const float* Qb = Q + (size_t)b * C_ * T_;
    const float* Kb = K + (size_t)b * C_ * T_;
    for (int half = 0; half < 2; ++half) {
        __syncthreads();
        const float4* src = (const float4*)(Kb + half * 128 * 64);
        float4* dst = (float4*)Ks;
        #pragma unroll
        for (int k = 0; k < 8; ++k) dst[k*256 + tid] = src[k*256 + tid];
        __syncthreads();
        for (int cl = 0; cl < 128; ++cl) {
            const float kv = Ks[cl*64 + lane];
            const float* qrow = Qb + (size_t)(half*128 + cl) * T_ + wv*16;  // wave-uniform
            #pragma unroll
            for (int t = 0; t < 16; ++t) acc[t] += kv * qrow[t];
        }
    }

    #pragma unroll
    for (int t = 0; t < 16; ++t) {
        float m = acc[t];
        #pragma unroll
        for (int off = 32; off; off >>= 1) m = fmaxf(m, __shfl_xor(m, off));
        const float e = __expf(acc[t] - m);
        float ssum = e;
        #pragma unroll
        for (int off = 32; off; off >>= 1) ssum += __shfl_xor(ssum, off);
        As[lane*65 + wv*16 + t] = e / ssum;
    }
    __syncthreads();

    // coalesced write-out of AT[b][s][t]
    float* ATb = AT + (size_t)b * T_ * T_;
    #pragma unroll
    for (int i = 0; i < 16; ++i) {
        const int idx = i*256 + tid;
        const int s = idx >> 6, t = idx & 63;
        ATb[idx] = As[s*65 + t];
    }
}

// ---------------- Kernel 3: PV + bilinear 8->64 upsample + blend (fused) ----------------
// grid: B*C blocks (one per plane), 256 threads.
// Fatt[t] = sum_s V[b,c,s] * AT[b][s][t]   (AT is 0.5 MB total -> L2-hot)
__global__ __launch_bounds__(256) void k_up(const float* __restrict__ AT,
                                            const float* __restrict__ V,
                                            const float* __restrict__ Frgb,
                                            const float* __restrict__ alphap,
                                            float* __restrict__ Out) {
    __shared__ float Vs[64];
    __shared__ float Ps[4][64];
    __shared__ float Fs[64];
    const int tid = threadIdx.x;
    const int plane = blockIdx.x;
    const int b = plane >> 8;
    if (tid < 64) Vs[tid] = V[(size_t)plane*64 + tid];
    __syncthreads();
    // PV: thread (sq=tid>>6, t=tid&63) sums 16 s values
    {
        const int t = tid & 63;
        const int sq = tid >> 6;
        const float* ATb = AT + (size_t)b * T_ * T_;
        float sum = 0.f;
        #pragma unroll
        for (int j = 0; j < 16; ++j) {
            const int s = sq*16 + j;
            sum = fmaf(Vs[s], ATb[s*64 + t], sum);   // coalesced, L2-hot
        }
        Ps[sq][t] = sum;
    }
    __syncthreads();
    if (tid < 64) Fs[tid] = Ps[0][tid] + Ps[1][tid] + Ps[2][tid] + Ps[3][tid];
    __syncthreads();

    const float alpha = alphap[0];
    const float beta = 1.f - alpha;
    const float4* rgb4 = (const float4*)Frgb + (size_t)plane * 1024;
    float4* out4 = (float4*)Out + (size_t)plane * 1024;
    #pragma unroll
    for (int k = 0; k < 4; ++k) {
        const int flat = k*1024 + tid*4;
        const int y  = flat >> 6;
        const int xb = flat & 63;
        const float sy = y * 0.125f - 0.4375f;
        const float fy = floorf(sy);
        const float wy = sy - fy;
        const int iy = (int)fy;
        const int y0 = iy < 0 ? 0 : iy;
        const int y1 = (iy + 1) > 7 ? 7 : (iy + 1);
        float4 rv = rgb4[k*256 + tid];
        float o[4];
        const float rs[4] = {rv.x, rv.y, rv.z, rv.w};
        #pragma unroll
        for (int j = 0; j < 4; ++j) {
            const int x = xb + j;
            const float sx = x * 0.125f - 0.4375f;
            const float fx = floorf(sx);
            const float wx = sx - fx;
            const int ix = (int)fx;
            const int x0 = ix < 0 ? 0 : ix;
            const int x1 = (ix + 1) > 7 ? 7 : (ix + 1);
            const float top = (1.f - wx) * Fs[y0*8 + x0] + wx * Fs[y0*8 + x1];
            const float bot = (1.f - wx) * Fs[y1*8 + x0] + wx * Fs[y1*8 + x1];
            const float v = (1.f - wy) * top + wy * bot;
            o[j] = alpha * v + beta * rs[j];
        }
        out4[k*256 + tid] = make_float4(o[0], o[1], o[2], o[3]);
    }
}

extern "C" void kernel_launch(void* const* d_in, const int* in_sizes, int n_in,
                              void* d_out, int out_size, void* d_ws, size_t ws_size,
                              hipStream_t stream) {
    const float* Frgb  = (const float*)d_in[0];
    const float* Fd    = (const float*)d_in[1];
    const float* Wq    = (const float*)d_in[2];
    const float* bq    = (const float*)d_in[3];
    const float* Wk    = (const float*)d_in[4];
    const float* bk    = (const float*)d_in[5];
    const float* Wv    = (const float*)d_in[6];
    const float* bv    = (const float*)d_in[7];
    const float* alpha = (const float*)d_in[8];

    float* ws = (float*)d_ws;
    const size_t PC = (size_t)B_ * C_ * T_;   // 524288 floats per pooled tensor
    float* R    = ws;
    float* D    = ws + PC;
    float* Q    = ws + 2*PC;
    float* K    = ws + 3*PC;
    float* V    = ws + 4*PC;
    float* AT   = ws + 5*PC;                  // 32*64*64 floats
    float* Out  = (float*)d_out;

    k_pool <<<B_*C_, 256, 0, stream>>>(Frgb, Fd, R, D);
    k_qkv  <<<dim3(4, 32, 3), 256, 0, stream>>>(R, D, Wq, bq, Wk, bk, Wv, bv, Q, K, V);
    k_attnA<<<B_, 256, 0, stream>>>(Q, K, AT);
    k_up   <<<B_*C_, 256, 0, stream>>>(AT, V, Frgb, alpha, Out);
}